// Round 3
// baseline (132.015 us; speedup 1.0000x reference)
//
#include <hip/hip_runtime.h>
#include <hip/hip_bf16.h>

// N=2048, D_IN=128, H=256, D_EMB=64
// inputs: 0:x 1:adj(unused) 2:W0 3:b0 4:W1 5:b1 6:W2 7:b2 8:temp 9:theta
// d_out: out[2048*128] then adj_wts[2048*2048]

typedef short bf16x8 __attribute__((ext_vector_type(8)));
typedef float f32x4 __attribute__((ext_vector_type(4)));

__device__ __forceinline__ unsigned short f2bf(float f) {
    unsigned u = __float_as_uint(f);
    unsigned r = u + 0x7fffu + ((u >> 16) & 1u);
    return (unsigned short)(r >> 16);
}

// ---------------- Kernel 1: fused MLP (f32) ----------------
// 256 blocks x 512 threads, 8 rows per block. Also zeroes deg.
__global__ __launch_bounds__(512) void k1_mlp(
    const float* __restrict__ x,
    const float* __restrict__ W0, const float* __restrict__ b0,
    const float* __restrict__ W1, const float* __restrict__ b1,
    const float* __restrict__ W2, const float* __restrict__ b2,
    unsigned short* __restrict__ emb_bf,   // [2048][64] bf16
    unsigned short* __restrict__ xlT_bf,   // [128][2048] bf16 (transposed x_last)
    float* __restrict__ sq,                // [2048]
    float* __restrict__ deg)               // [2048] zeroed here for k2a atomics
{
    __shared__ float xs[8 * 132];
    __shared__ float oxs[8 * 260];
    __shared__ unsigned short xls[128 * 8];
    const int t = threadIdx.x;
    const int r0 = blockIdx.x * 8;

    if (t < 256) {
        int row = t >> 5, c4 = t & 31;
        float4 v = *(const float4*)(x + (r0 + row) * 128 + c4 * 4);
        *(float4*)(&xs[row * 132 + c4 * 4]) = v;
    }
    if (t < 8) deg[r0 + t] = 0.0f;
    __syncthreads();

    // Phase A: out_x = relu(x@W0+b0). col c=t&255, rows rg*4..+3
    {
        int c = t & 255, rg = t >> 8;
        float bb = b0[c];
        float acc[4] = {bb, bb, bb, bb};
        for (int kk = 0; kk < 32; ++kk) {
            float wa = W0[(kk * 4 + 0) * 256 + c];
            float wb = W0[(kk * 4 + 1) * 256 + c];
            float wc = W0[(kk * 4 + 2) * 256 + c];
            float wd = W0[(kk * 4 + 3) * 256 + c];
            #pragma unroll
            for (int r = 0; r < 4; ++r) {
                float4 xv = *(const float4*)(&xs[(rg * 4 + r) * 132 + kk * 4]);
                acc[r] += xv.x * wa + xv.y * wb + xv.z * wc + xv.w * wd;
            }
        }
        #pragma unroll
        for (int r = 0; r < 4; ++r) oxs[(rg * 4 + r) * 260 + c] = fmaxf(acc[r], 0.0f);
    }
    __syncthreads();

    // Phase B: emb = relu(out_x@W1+b1). row r=t>>6 (one per wave), col h=t&63
    {
        int h = t & 63, r = t >> 6;
        float acc = b1[h];
        for (int kk = 0; kk < 64; ++kk) {
            float wa = W1[(kk * 4 + 0) * 64 + h];
            float wb = W1[(kk * 4 + 1) * 64 + h];
            float wc = W1[(kk * 4 + 2) * 64 + h];
            float wd = W1[(kk * 4 + 3) * 64 + h];
            float4 xv = *(const float4*)(&oxs[r * 260 + kk * 4]);
            acc += xv.x * wa + xv.y * wb + xv.z * wc + xv.w * wd;
        }
        float e = fmaxf(acc, 0.0f);
        emb_bf[(r0 + r) * 64 + h] = f2bf(e);
        float s = e * e;
        #pragma unroll
        for (int off = 32; off; off >>= 1) s += __shfl_xor(s, off);
        if (h == 0) sq[r0 + r] = s;
    }

    // Phase C: x_last = x@W2+b2 (no relu). col c=t&127, rows rg*2..+1
    {
        int c = t & 127, rg = t >> 7;
        float bb = b2[c];
        float acc[2] = {bb, bb};
        for (int kk = 0; kk < 32; ++kk) {
            float wa = W2[(kk * 4 + 0) * 128 + c];
            float wb = W2[(kk * 4 + 1) * 128 + c];
            float wc = W2[(kk * 4 + 2) * 128 + c];
            float wd = W2[(kk * 4 + 3) * 128 + c];
            #pragma unroll
            for (int r = 0; r < 2; ++r) {
                float4 xv = *(const float4*)(&xs[(rg * 2 + r) * 132 + kk * 4]);
                acc[r] += xv.x * wa + xv.y * wb + xv.z * wc + xv.w * wd;
            }
        }
        unsigned short p0 = f2bf(acc[0]), p1 = f2bf(acc[1]);
        *(unsigned int*)(&xls[c * 8 + rg * 2]) = (unsigned)p0 | ((unsigned)p1 << 16);
    }
    __syncthreads();
    if (t < 128) {
        uint4 v = *(const uint4*)(&xls[t * 8]);
        *(uint4*)(&xlT_bf[t * 2048 + r0]) = v;
    }
}

// ---------------- Kernel 2a: adjacency tiles (independent blocks) ----------------
// grid (32 i-tiles x 16 j-tiles) x 256 thr. Block: 64x128 tile of A. ONE barrier.
__global__ __launch_bounds__(256) void k2a(
    const unsigned short* __restrict__ emb_bf,
    const float* __restrict__ sq,
    const float* __restrict__ tempp, const float* __restrict__ thetap,
    float* __restrict__ adjw,          // [2048][2048] f32 (output adj_wts)
    unsigned short* __restrict__ A_bf, // [2048][2048] bf16 copy for k2b
    float* __restrict__ deg)           // [2048] atomic accumulate
{
    constexpr int LD = 72;
    __shared__ unsigned short embI[64 * LD];
    __shared__ unsigned short embJ[128 * LD];
    __shared__ float sqI[64];
    __shared__ float sqJ[128];

    const int t = threadIdx.x;
    const int lane = t & 63;
    const int w = t >> 6;        // wave 0..3
    const int m = lane & 15;
    const int q = lane >> 4;
    const int i0 = blockIdx.x * 64;
    const int j0 = blockIdx.y * 128;
    const float scale = 1.0f + tempp[0];
    const float bias = 5.0f + thetap[0];

    for (int ch = t; ch < 512; ch += 256) {
        int row = ch >> 3, off = ch & 7;
        *(uint4*)(&embI[row * LD + off * 8]) =
            *(const uint4*)(emb_bf + (i0 + row) * 64 + off * 8);
    }
    for (int ch = t; ch < 1024; ch += 256) {
        int row = ch >> 3, off = ch & 7;
        *(uint4*)(&embJ[row * LD + off * 8]) =
            *(const uint4*)(emb_bf + (j0 + row) * 64 + off * 8);
    }
    if (t < 64) sqI[t] = sq[i0 + t];
    if (t >= 64 && t < 192) sqJ[t - 64] = sq[j0 + t - 64];
    __syncthreads();

    // wave w handles rows irow..irow+15, all 128 cols (8 j-subtiles)
    const int irow = w * 16;
    bf16x8 a0 = *(const bf16x8*)(&embI[(irow + m) * LD + q * 8]);
    bf16x8 a1 = *(const bf16x8*)(&embI[(irow + m) * LD + 32 + q * 8]);
    float dega[4] = {0.f, 0.f, 0.f, 0.f};

    #pragma unroll
    for (int jc = 0; jc < 8; ++jc) {
        int jcol = jc * 16 + m;
        bf16x8 b0 = *(const bf16x8*)(&embJ[jcol * LD + q * 8]);
        bf16x8 b1 = *(const bf16x8*)(&embJ[jcol * LD + 32 + q * 8]);
        f32x4 S = {0.f, 0.f, 0.f, 0.f};
        S = __builtin_amdgcn_mfma_f32_16x16x32_bf16(a0, b0, S, 0, 0, 0);
        S = __builtin_amdgcn_mfma_f32_16x16x32_bf16(a1, b1, S, 0, 0, 0);

        float csqJ = sqJ[jc * 16 + m];
        int gcol = j0 + jc * 16 + m;
        #pragma unroll
        for (int r = 0; r < 4; ++r) {
            int lrow = irow + q * 4 + r;
            int grow = i0 + lrow;
            float dist = 2.0f * S[r] - sqI[lrow] - csqJ;
            float z = scale * dist + bias;
            float p = 1.0f / (1.0f + __expf(-z));
            if (grow == gcol) p += 1.0f;
            adjw[(size_t)grow * 2048 + gcol] = p;
            A_bf[(size_t)grow * 2048 + gcol] = f2bf(p);
            dega[r] += p;
        }
    }
    // deg: reduce over the 16 m-lanes, one atomic per (row, j-block)
    #pragma unroll
    for (int r = 0; r < 4; ++r) {
        float v = dega[r];
        v += __shfl_xor(v, 1);
        v += __shfl_xor(v, 2);
        v += __shfl_xor(v, 4);
        v += __shfl_xor(v, 8);
        if (m == 0) atomicAdd(&deg[i0 + irow + q * 4 + r], v);
    }
}

// ---------------- Kernel 2b: out = relu((A@x_last)/deg) ----------------
// 128 blocks x 512 thr (8 waves): 4 col-groups x 2 K-halves; no barrier in K-loop.
__global__ __launch_bounds__(512) void k2b(
    const unsigned short* __restrict__ A_bf,
    const unsigned short* __restrict__ xlT_bf,
    const float* __restrict__ deg,
    float* __restrict__ out)
{
    __shared__ float part[2 * 16 * 128];  // [kh][row][col], 16 KB
    const int t = threadIdx.x;
    const int lane = t & 63;
    const int w = t >> 6;            // 0..7
    const int m = lane & 15;
    const int q = lane >> 4;
    const int i0 = blockIdx.x * 16;
    const int cg = (w & 3) * 32;     // column group base
    const int kh = w >> 2;           // K half (0/1)

    const unsigned short* Arow = A_bf + (size_t)(i0 + m) * 2048 + kh * 1024;
    const unsigned short* B0 = xlT_bf + (size_t)(cg + m) * 2048 + kh * 1024;
    const unsigned short* B1 = xlT_bf + (size_t)(cg + 16 + m) * 2048 + kh * 1024;

    f32x4 acc0 = {0.f, 0.f, 0.f, 0.f};
    f32x4 acc1 = {0.f, 0.f, 0.f, 0.f};
    #pragma unroll 4
    for (int kk = 0; kk < 1024; kk += 32) {
        bf16x8 a  = *(const bf16x8*)(Arow + kk + q * 8);
        bf16x8 b0 = *(const bf16x8*)(B0 + kk + q * 8);
        bf16x8 b1 = *(const bf16x8*)(B1 + kk + q * 8);
        acc0 = __builtin_amdgcn_mfma_f32_16x16x32_bf16(a, b0, acc0, 0, 0, 0);
        acc1 = __builtin_amdgcn_mfma_f32_16x16x32_bf16(a, b1, acc1, 0, 0, 0);
    }
    #pragma unroll
    for (int r = 0; r < 4; ++r) {
        part[kh * 2048 + (q * 4 + r) * 128 + cg + m] = acc0[r];
        part[kh * 2048 + (q * 4 + r) * 128 + cg + 16 + m] = acc1[r];
    }
    __syncthreads();
    for (int idx = t; idx < 2048; idx += 512) {
        int r = idx >> 7, c = idx & 127;
        float s = part[r * 128 + c] + part[2048 + r * 128 + c];
        out[(size_t)(i0 + r) * 128 + c] = fmaxf(s / deg[i0 + r], 0.0f);
    }
}

extern "C" void kernel_launch(void* const* d_in, const int* in_sizes, int n_in,
                              void* d_out, int out_size, void* d_ws, size_t ws_size,
                              hipStream_t stream) {
    const float* x     = (const float*)d_in[0];
    const float* W0    = (const float*)d_in[2];
    const float* b0    = (const float*)d_in[3];
    const float* W1    = (const float*)d_in[4];
    const float* b1    = (const float*)d_in[5];
    const float* W2    = (const float*)d_in[6];
    const float* b2    = (const float*)d_in[7];
    const float* temp  = (const float*)d_in[8];
    const float* theta = (const float*)d_in[9];

    // workspace layout
    char* ws = (char*)d_ws;
    unsigned short* emb_bf = (unsigned short*)(ws);            // 262144 B
    unsigned short* xlT_bf = (unsigned short*)(ws + 262144);   // 524288 B
    float* sq   = (float*)(ws + 786432);                       //   8192 B
    float* deg  = (float*)(ws + 794624);                       //   8192 B
    unsigned short* A_bf = (unsigned short*)(ws + 802816);     // 8388608 B

    float* out  = (float*)d_out;              // [2048*128]
    float* adjw = (float*)d_out + 262144;     // [2048*2048]

    k1_mlp<<<256, 512, 0, stream>>>(x, W0, b0, W1, b1, W2, b2,
                                    emb_bf, xlT_bf, sq, deg);
    k2a<<<dim3(32, 16), 256, 0, stream>>>(emb_bf, sq, temp, theta,
                                          adjw, A_bf, deg);
    k2b<<<128, 512, 0, stream>>>(A_bf, xlT_bf, deg, out);
}

// Round 4
// 126.282 us; speedup vs baseline: 1.0454x; 1.0454x over previous
//
#include <hip/hip_runtime.h>
#include <hip/hip_bf16.h>

// N=2048, D_IN=128, H=256, D_EMB=64
// inputs: 0:x 1:adj(unused) 2:W0 3:b0 4:W1 5:b1 6:W2 7:b2 8:temp 9:theta
// d_out: out[2048*128] then adj_wts[2048*2048]

typedef short bf16x8 __attribute__((ext_vector_type(8)));
typedef float f32x4 __attribute__((ext_vector_type(4)));

__device__ __forceinline__ unsigned short f2bf(float f) {
    unsigned u = __float_as_uint(f);
    unsigned r = u + 0x7fffu + ((u >> 16) & 1u);
    return (unsigned short)(r >> 16);
}

// truncation-pack 8 f32 -> bf16x8 (1 v_perm per pair; bias negligible here)
__device__ __forceinline__ bf16x8 pack_bf8(const float* p) {
    union { unsigned u[4]; bf16x8 v; } r;
    #pragma unroll
    for (int i = 0; i < 4; ++i)
        r.u[i] = __builtin_amdgcn_perm(__float_as_uint(p[2 * i + 1]),
                                       __float_as_uint(p[2 * i]), 0x07060302u);
    return r.v;
}

// ---------------- Kernel 1: fused MLP (f32) ----------------
// 256 blocks x 512 threads, 8 rows per block. Also zeroes deg and outAcc.
__global__ __launch_bounds__(512) void k1_mlp(
    const float* __restrict__ x,
    const float* __restrict__ W0, const float* __restrict__ b0,
    const float* __restrict__ W1, const float* __restrict__ b1,
    const float* __restrict__ W2, const float* __restrict__ b2,
    unsigned short* __restrict__ emb_bf,   // [2048][64] bf16
    unsigned short* __restrict__ xlT_bf,   // [128][2048] bf16 (transposed x_last)
    float* __restrict__ sq,                // [2048]
    float* __restrict__ deg,               // [2048] zeroed for k2 atomics
    float* __restrict__ outAcc)            // [2048*128] zeroed for k2 atomics
{
    __shared__ float xs[8 * 132];
    __shared__ float oxs[8 * 260];
    __shared__ unsigned short xls[128 * 8];
    const int t = threadIdx.x;
    const int r0 = blockIdx.x * 8;

    if (t < 256) {
        int row = t >> 5, c4 = t & 31;
        float4 v = *(const float4*)(x + (r0 + row) * 128 + c4 * 4);
        *(float4*)(&xs[row * 132 + c4 * 4]) = v;
    }
    if (t < 8) deg[r0 + t] = 0.0f;
    // zero this block's slice of outAcc: 1024 f32 per block
    *(float2*)(&outAcc[blockIdx.x * 1024 + t * 2]) = make_float2(0.f, 0.f);
    __syncthreads();

    // Phase A: out_x = relu(x@W0+b0). col c=t&255, rows rg*4..+3
    {
        int c = t & 255, rg = t >> 8;
        float bb = b0[c];
        float acc[4] = {bb, bb, bb, bb};
        for (int kk = 0; kk < 32; ++kk) {
            float wa = W0[(kk * 4 + 0) * 256 + c];
            float wb = W0[(kk * 4 + 1) * 256 + c];
            float wc = W0[(kk * 4 + 2) * 256 + c];
            float wd = W0[(kk * 4 + 3) * 256 + c];
            #pragma unroll
            for (int r = 0; r < 4; ++r) {
                float4 xv = *(const float4*)(&xs[(rg * 4 + r) * 132 + kk * 4]);
                acc[r] += xv.x * wa + xv.y * wb + xv.z * wc + xv.w * wd;
            }
        }
        #pragma unroll
        for (int r = 0; r < 4; ++r) oxs[(rg * 4 + r) * 260 + c] = fmaxf(acc[r], 0.0f);
    }
    __syncthreads();

    // Phase B: emb = relu(out_x@W1+b1). row r=t>>6 (one per wave), col h=t&63
    {
        int h = t & 63, r = t >> 6;
        float acc = b1[h];
        for (int kk = 0; kk < 64; ++kk) {
            float wa = W1[(kk * 4 + 0) * 64 + h];
            float wb = W1[(kk * 4 + 1) * 64 + h];
            float wc = W1[(kk * 4 + 2) * 64 + h];
            float wd = W1[(kk * 4 + 3) * 64 + h];
            float4 xv = *(const float4*)(&oxs[r * 260 + kk * 4]);
            acc += xv.x * wa + xv.y * wb + xv.z * wc + xv.w * wd;
        }
        float e = fmaxf(acc, 0.0f);
        emb_bf[(r0 + r) * 64 + h] = f2bf(e);
        float s = e * e;
        #pragma unroll
        for (int off = 32; off; off >>= 1) s += __shfl_xor(s, off);
        if (h == 0) sq[r0 + r] = s;
    }

    // Phase C: x_last = x@W2+b2 (no relu). col c=t&127, rows rg*2..+1
    {
        int c = t & 127, rg = t >> 7;
        float bb = b2[c];
        float acc[2] = {bb, bb};
        for (int kk = 0; kk < 32; ++kk) {
            float wa = W2[(kk * 4 + 0) * 128 + c];
            float wb = W2[(kk * 4 + 1) * 128 + c];
            float wc = W2[(kk * 4 + 2) * 128 + c];
            float wd = W2[(kk * 4 + 3) * 128 + c];
            #pragma unroll
            for (int r = 0; r < 2; ++r) {
                float4 xv = *(const float4*)(&xs[(rg * 2 + r) * 132 + kk * 4]);
                acc[r] += xv.x * wa + xv.y * wb + xv.z * wc + xv.w * wd;
            }
        }
        unsigned short p0 = f2bf(acc[0]), p1 = f2bf(acc[1]);
        *(unsigned int*)(&xls[c * 8 + rg * 2]) = (unsigned)p0 | ((unsigned)p1 << 16);
    }
    __syncthreads();
    if (t < 128) {
        uint4 v = *(const uint4*)(&xls[t * 8]);
        *(uint4*)(&xlT_bf[t * 2048 + r0]) = v;
    }
}

// ---------------- Kernel 2: fused adjacency + A@x_last ----------------
// grid (128 i-tiles, 8 j-strips) x 256 thr (4 waves). Block: 16 i-rows x 256 j-cols
// in 2 iterations of 128 cols. ONE barrier per iteration (double-buffered P tile).
// All MFMA fragments load directly from global (inputs are L2-resident).
__global__ __launch_bounds__(256) void k2f(
    const unsigned short* __restrict__ emb_bf,
    const unsigned short* __restrict__ xlT_bf,
    const float* __restrict__ sq,
    const float* __restrict__ tempp, const float* __restrict__ thetap,
    float* __restrict__ adjw,     // [2048][2048] f32
    float* __restrict__ outAcc,   // [2048][128] f32, atomic accumulate
    float* __restrict__ deg)      // [2048] atomic accumulate
{
    constexpr int LDP = 132;                 // f32 row stride (2-way bank pattern)
    __shared__ float Pt[2][16 * LDP];        // 16.9 KB total

    const int t = threadIdx.x;
    const int lane = t & 63;
    const int w = t >> 6;        // wave 0..3
    const int m = lane & 15;
    const int q = lane >> 4;
    const int i0 = blockIdx.x * 16;
    const int jstrip0 = blockIdx.y * 256;
    const float scale = 1.0f + tempp[0];
    const float bias = 5.0f + thetap[0];

    // hoisted A-fragments (rows i0..i0+15, K=64) and sqI
    bf16x8 a0 = *(const bf16x8*)(emb_bf + (size_t)(i0 + m) * 64 + q * 8);
    bf16x8 a1 = *(const bf16x8*)(emb_bf + (size_t)(i0 + m) * 64 + 32 + q * 8);
    float sqIr[4];
    #pragma unroll
    for (int r = 0; r < 4; ++r) sqIr[r] = sq[i0 + q * 4 + r];

    f32x4 accO0 = {0.f, 0.f, 0.f, 0.f};
    f32x4 accO1 = {0.f, 0.f, 0.f, 0.f};
    float dega[4] = {0.f, 0.f, 0.f, 0.f};
    const int cg = w * 32;

    #pragma unroll
    for (int jt = 0; jt < 2; ++jt) {
        const int j0 = jstrip0 + jt * 128;
        float* P = &Pt[jt][0];

        // ---- S phase: wave w computes cols 32w..32w+31 (2 subtiles) ----
        #pragma unroll
        for (int s = 0; s < 2; ++s) {
            const int col = (w * 2 + s) * 16 + m;
            const unsigned short* ebj = emb_bf + (size_t)(j0 + col) * 64;
            bf16x8 b0 = *(const bf16x8*)(ebj + q * 8);
            bf16x8 b1 = *(const bf16x8*)(ebj + 32 + q * 8);
            f32x4 S = {0.f, 0.f, 0.f, 0.f};
            S = __builtin_amdgcn_mfma_f32_16x16x32_bf16(a0, b0, S, 0, 0, 0);
            S = __builtin_amdgcn_mfma_f32_16x16x32_bf16(a1, b1, S, 0, 0, 0);

            const float csqJ = sq[j0 + col];
            const int gcol = j0 + col;
            #pragma unroll
            for (int r = 0; r < 4; ++r) {
                int grow = i0 + q * 4 + r;
                float dist = 2.0f * S[r] - sqIr[r] - csqJ;
                float z = scale * dist + bias;
                float p = 1.0f / (1.0f + __expf(-z));
                if (grow == gcol) p += 1.0f;
                dega[r] += p;
                P[(q * 4 + r) * LDP + col] = p;
            }
        }
        __syncthreads();   // the only barrier this iteration

        // ---- adjw store: full tile, coalesced 128B lines, nontemporal ----
        {
            int row = t >> 4;
            int c0 = (t & 15) * 8;
            f32x4 v0 = *(const f32x4*)(&P[row * LDP + c0]);
            f32x4 v1 = *(const f32x4*)(&P[row * LDP + c0 + 4]);
            f32x4* dst = (f32x4*)(adjw + (size_t)(i0 + row) * 2048 + j0 + c0);
            __builtin_nontemporal_store(v0, dst);
            __builtin_nontemporal_store(v1, dst + 1);
        }

        // ---- AX phase: acc += P(16x128) @ xlT(cols cg..cg+31, K=128) ----
        #pragma unroll
        for (int s = 0; s < 4; ++s) {
            float af[8];
            *(f32x4*)(&af[0]) = *(const f32x4*)(&P[m * LDP + s * 32 + q * 8]);
            *(f32x4*)(&af[4]) = *(const f32x4*)(&P[m * LDP + s * 32 + q * 8 + 4]);
            bf16x8 aa = pack_bf8(af);
            const int k = j0 + s * 32 + q * 8;
            bf16x8 b0 = *(const bf16x8*)(xlT_bf + (size_t)(cg + m) * 2048 + k);
            bf16x8 b1 = *(const bf16x8*)(xlT_bf + (size_t)(cg + 16 + m) * 2048 + k);
            accO0 = __builtin_amdgcn_mfma_f32_16x16x32_bf16(aa, b0, accO0, 0, 0, 0);
            accO1 = __builtin_amdgcn_mfma_f32_16x16x32_bf16(aa, b1, accO1, 0, 0, 0);
        }
        // next iter writes Pt[1] while no one re-reads Pt[0] -> no extra barrier
    }

    // ---- deg: reduce over the 16 m-lanes, one atomic per (wave,row) ----
    #pragma unroll
    for (int r = 0; r < 4; ++r) {
        float v = dega[r];
        v += __shfl_xor(v, 1);
        v += __shfl_xor(v, 2);
        v += __shfl_xor(v, 4);
        v += __shfl_xor(v, 8);
        if (m == 0) atomicAdd(&deg[i0 + q * 4 + r], v);
    }
    // ---- out partial accumulate ----
    #pragma unroll
    for (int r = 0; r < 4; ++r) {
        int row = i0 + q * 4 + r;
        atomicAdd(&outAcc[row * 128 + cg + m], accO0[r]);
        atomicAdd(&outAcc[row * 128 + cg + 16 + m], accO1[r]);
    }
}

// ---------------- Kernel 3: out = relu(out/deg) in place ----------------
__global__ __launch_bounds__(256) void k3_fin(float* __restrict__ out,
                                              const float* __restrict__ deg) {
    int idx = blockIdx.x * 1024 + threadIdx.x * 4;
    float4 v = *(float4*)(&out[idx]);
    float dinv = 1.0f / deg[idx >> 7];
    v.x = fmaxf(v.x * dinv, 0.f);
    v.y = fmaxf(v.y * dinv, 0.f);
    v.z = fmaxf(v.z * dinv, 0.f);
    v.w = fmaxf(v.w * dinv, 0.f);
    *(float4*)(&out[idx]) = v;
}

extern "C" void kernel_launch(void* const* d_in, const int* in_sizes, int n_in,
                              void* d_out, int out_size, void* d_ws, size_t ws_size,
                              hipStream_t stream) {
    const float* x     = (const float*)d_in[0];
    const float* W0    = (const float*)d_in[2];
    const float* b0    = (const float*)d_in[3];
    const float* W1    = (const float*)d_in[4];
    const float* b1    = (const float*)d_in[5];
    const float* W2    = (const float*)d_in[6];
    const float* b2    = (const float*)d_in[7];
    const float* temp  = (const float*)d_in[8];
    const float* theta = (const float*)d_in[9];

    char* ws = (char*)d_ws;
    unsigned short* emb_bf = (unsigned short*)(ws);            // 262144 B
    unsigned short* xlT_bf = (unsigned short*)(ws + 262144);   // 524288 B
    float* sq  = (float*)(ws + 786432);                        //   8192 B
    float* deg = (float*)(ws + 794624);                        //   8192 B

    float* outAcc = (float*)d_out;            // [2048*128]
    float* adjw   = (float*)d_out + 262144;   // [2048*2048]

    k1_mlp<<<256, 512, 0, stream>>>(x, W0, b0, W1, b1, W2, b2,
                                    emb_bf, xlT_bf, sq, deg, outAcc);
    k2f<<<dim3(128, 8), 256, 0, stream>>>(emb_bf, xlT_bf, sq, temp, theta,
                                          adjw, outAcc, deg);
    k3_fin<<<256, 256, 0, stream>>>(outAcc, deg);
}

// Round 5
// 113.386 us; speedup vs baseline: 1.1643x; 1.1137x over previous
//
#include <hip/hip_runtime.h>
#include <hip/hip_bf16.h>

// N=2048, D_IN=128, H=256, D_EMB=64
// inputs: 0:x 1:adj(unused) 2:W0 3:b0 4:W1 5:b1 6:W2 7:b2 8:temp 9:theta
// d_out: out[2048*128] then adj_wts[2048*2048]

typedef short bf16x8 __attribute__((ext_vector_type(8)));
typedef float f32x4 __attribute__((ext_vector_type(4)));

__device__ __forceinline__ unsigned short f2bf(float f) {
    unsigned u = __float_as_uint(f);
    unsigned r = u + 0x7fffu + ((u >> 16) & 1u);
    return (unsigned short)(r >> 16);
}

// pack 8 f32 -> bf16x8 with round-half-up (1 add + shared perm per pair)
__device__ __forceinline__ bf16x8 pack_rne8(const float* p) {
    union { unsigned u[4]; bf16x8 v; } r;
    #pragma unroll
    for (int i = 0; i < 4; ++i) {
        unsigned lo = __float_as_uint(p[2 * i]) + 0x8000u;
        unsigned hi = __float_as_uint(p[2 * i + 1]) + 0x8000u;
        r.u[i] = __builtin_amdgcn_perm(hi, lo, 0x07060302u);
    }
    return r.v;
}

// truncation-pack (for the already-rounded P tile in k2)
__device__ __forceinline__ bf16x8 pack_bf8(const float* p) {
    union { unsigned u[4]; bf16x8 v; } r;
    #pragma unroll
    for (int i = 0; i < 4; ++i)
        r.u[i] = __builtin_amdgcn_perm(__float_as_uint(p[2 * i + 1]),
                                       __float_as_uint(p[2 * i]), 0x07060302u);
    return r.v;
}

// ---------------- Kernel 1: fused MLP via MFMA ----------------
// grid 128 x 256 thr (4 waves). Block: 16 rows. All weights loaded from global
// (L2-resident), packed to bf16 in-reg. out_x goes through LDS. 2 barriers.
__global__ __launch_bounds__(256) void k1_mfma(
    const float* __restrict__ x,
    const float* __restrict__ W0, const float* __restrict__ b0,
    const float* __restrict__ W1, const float* __restrict__ b1,
    const float* __restrict__ W2, const float* __restrict__ b2,
    unsigned short* __restrict__ emb_bf,   // [2048][64] bf16
    unsigned short* __restrict__ xlT_bf,   // [128][2048] bf16
    float* __restrict__ sq)                // [2048]
{
    constexpr int LDO = 264;               // out_x LDS stride (bf16 elems)
    __shared__ unsigned short oxb[16 * LDO];
    __shared__ float sqs[4][16];

    const int t = threadIdx.x;
    const int lane = t & 63;
    const int w = t >> 6;      // wave 0..3
    const int m = lane & 15;
    const int q = lane >> 4;
    const int i0 = blockIdx.x * 16;

    // A-fragments of x (rows i0+m, K=128), shared by GEMM0 and GEMM2
    bf16x8 ax[4];
    #pragma unroll
    for (int kb = 0; kb < 4; ++kb) {
        float xf[8];
        *(f32x4*)&xf[0] = *(const f32x4*)(x + (size_t)(i0 + m) * 128 + kb * 32 + q * 8);
        *(f32x4*)&xf[4] = *(const f32x4*)(x + (size_t)(i0 + m) * 128 + kb * 32 + q * 8 + 4);
        ax[kb] = pack_rne8(xf);
    }

    // ---- GEMM0: out_x = relu(x @ W0 + b0), wave w covers cols w*64..w*64+63 ----
    #pragma unroll
    for (int hh = 0; hh < 4; ++hh) {
        const int h = (w * 4 + hh) * 16 + m;
        float bb = b0[h];
        f32x4 acc = {bb, bb, bb, bb};
        #pragma unroll
        for (int kb = 0; kb < 4; ++kb) {
            float wf[8];
            #pragma unroll
            for (int j = 0; j < 8; ++j) wf[j] = W0[(size_t)(kb * 32 + q * 8 + j) * 256 + h];
            acc = __builtin_amdgcn_mfma_f32_16x16x32_bf16(ax[kb], pack_rne8(wf), acc, 0, 0, 0);
        }
        #pragma unroll
        for (int r = 0; r < 4; ++r)
            oxb[(q * 4 + r) * LDO + h] = f2bf(fmaxf(acc[r], 0.0f));
    }
    __syncthreads();

    // ---- GEMM1: emb = relu(out_x @ W1 + b1), wave w covers cols w*16..w*16+15 ----
    {
        const int h = w * 16 + m;
        float bb = b1[h];
        f32x4 acc = {bb, bb, bb, bb};
        #pragma unroll
        for (int kb = 0; kb < 8; ++kb) {
            bf16x8 af = *(const bf16x8*)(&oxb[m * LDO + kb * 32 + q * 8]);
            float wf[8];
            #pragma unroll
            for (int j = 0; j < 8; ++j) wf[j] = W1[(size_t)(kb * 32 + q * 8 + j) * 64 + h];
            acc = __builtin_amdgcn_mfma_f32_16x16x32_bf16(af, pack_rne8(wf), acc, 0, 0, 0);
        }
        float s2[4];
        #pragma unroll
        for (int r = 0; r < 4; ++r) {
            float e = fmaxf(acc[r], 0.0f);
            emb_bf[(size_t)(i0 + q * 4 + r) * 64 + h] = f2bf(e);
            s2[r] = e * e;
        }
        // reduce e^2 over the 16 m-lanes -> per-(wave,row) partial
        #pragma unroll
        for (int r = 0; r < 4; ++r) {
            float v = s2[r];
            v += __shfl_xor(v, 1);
            v += __shfl_xor(v, 2);
            v += __shfl_xor(v, 4);
            v += __shfl_xor(v, 8);
            if (m == 0) sqs[w][q * 4 + r] = v;
        }
    }

    // ---- GEMM2: x_last = x @ W2 + b2 (no relu), wave w covers cols w*32..w*32+31 ----
    #pragma unroll
    for (int hh = 0; hh < 2; ++hh) {
        const int c = (w * 2 + hh) * 16 + m;
        float bb = b2[c];
        f32x4 acc = {bb, bb, bb, bb};
        #pragma unroll
        for (int kb = 0; kb < 4; ++kb) {
            float wf[8];
            #pragma unroll
            for (int j = 0; j < 8; ++j) wf[j] = W2[(size_t)(kb * 32 + q * 8 + j) * 128 + c];
            acc = __builtin_amdgcn_mfma_f32_16x16x32_bf16(ax[kb], pack_rne8(wf), acc, 0, 0, 0);
        }
        // store transposed: xlT[c][i0+q*4 .. +3], 8B per lane
        uint2 pk;
        pk.x = (unsigned)f2bf(acc[0]) | ((unsigned)f2bf(acc[1]) << 16);
        pk.y = (unsigned)f2bf(acc[2]) | ((unsigned)f2bf(acc[3]) << 16);
        *(uint2*)(&xlT_bf[(size_t)c * 2048 + i0 + q * 4]) = pk;
    }
    __syncthreads();
    if (t < 16)
        sq[i0 + t] = sqs[0][t] + sqs[1][t] + sqs[2][t] + sqs[3][t];
}

// ---------------- Kernel 2: fused adjacency + A@x_last (partial stores) ----------------
// grid (128 i-tiles, 8 j-strips) x 256 thr. Block: 16 rows x 256 cols in 2 iters.
// ONE barrier per iteration; no atomics anywhere.
__global__ __launch_bounds__(256) void k2f(
    const unsigned short* __restrict__ emb_bf,
    const unsigned short* __restrict__ xlT_bf,
    const float* __restrict__ sq,
    const float* __restrict__ tempp, const float* __restrict__ thetap,
    float* __restrict__ adjw,      // [2048][2048] f32
    float* __restrict__ outPart,   // [8][2048][128]
    float* __restrict__ degPart)   // [8][2048]
{
    constexpr int LDP = 132;
    __shared__ float Pt[2][16 * LDP];
    __shared__ float degS[4][16];

    const int t = threadIdx.x;
    const int lane = t & 63;
    const int w = t >> 6;
    const int m = lane & 15;
    const int q = lane >> 4;
    const int i0 = blockIdx.x * 16;
    const int bj = blockIdx.y;
    const int jstrip0 = bj * 256;
    const float scale = 1.0f + tempp[0];
    const float bias = 5.0f + thetap[0];

    bf16x8 a0 = *(const bf16x8*)(emb_bf + (size_t)(i0 + m) * 64 + q * 8);
    bf16x8 a1 = *(const bf16x8*)(emb_bf + (size_t)(i0 + m) * 64 + 32 + q * 8);
    float sqIr[4];
    #pragma unroll
    for (int r = 0; r < 4; ++r) sqIr[r] = sq[i0 + q * 4 + r];

    f32x4 accO0 = {0.f, 0.f, 0.f, 0.f};
    f32x4 accO1 = {0.f, 0.f, 0.f, 0.f};
    float dega[4] = {0.f, 0.f, 0.f, 0.f};
    const int cg = w * 32;

    #pragma unroll
    for (int jt = 0; jt < 2; ++jt) {
        const int j0 = jstrip0 + jt * 128;
        float* P = &Pt[jt][0];

        #pragma unroll
        for (int s = 0; s < 2; ++s) {
            const int col = (w * 2 + s) * 16 + m;
            const unsigned short* ebj = emb_bf + (size_t)(j0 + col) * 64;
            bf16x8 b0 = *(const bf16x8*)(ebj + q * 8);
            bf16x8 b1 = *(const bf16x8*)(ebj + 32 + q * 8);
            f32x4 S = {0.f, 0.f, 0.f, 0.f};
            S = __builtin_amdgcn_mfma_f32_16x16x32_bf16(a0, b0, S, 0, 0, 0);
            S = __builtin_amdgcn_mfma_f32_16x16x32_bf16(a1, b1, S, 0, 0, 0);

            const float csqJ = sq[j0 + col];
            const int gcol = j0 + col;
            #pragma unroll
            for (int r = 0; r < 4; ++r) {
                int grow = i0 + q * 4 + r;
                float dist = 2.0f * S[r] - sqIr[r] - csqJ;
                float z = scale * dist + bias;
                float p = 1.0f / (1.0f + __expf(-z));
                if (grow == gcol) p += 1.0f;
                dega[r] += p;
                P[(q * 4 + r) * LDP + col] = p;
            }
        }
        __syncthreads();

        // adjw store: coalesced 128B lines, nontemporal
        {
            int row = t >> 4;
            int c0 = (t & 15) * 8;
            f32x4 v0 = *(const f32x4*)(&P[row * LDP + c0]);
            f32x4 v1 = *(const f32x4*)(&P[row * LDP + c0 + 4]);
            f32x4* dst = (f32x4*)(adjw + (size_t)(i0 + row) * 2048 + j0 + c0);
            __builtin_nontemporal_store(v0, dst);
            __builtin_nontemporal_store(v1, dst + 1);
        }

        // AX: acc += P(16x128) @ xlT(cols cg..cg+31, K=128)
        #pragma unroll
        for (int s = 0; s < 4; ++s) {
            float af[8];
            *(f32x4*)(&af[0]) = *(const f32x4*)(&P[m * LDP + s * 32 + q * 8]);
            *(f32x4*)(&af[4]) = *(const f32x4*)(&P[m * LDP + s * 32 + q * 8 + 4]);
            bf16x8 aa = pack_bf8(af);
            const int k = j0 + s * 32 + q * 8;
            bf16x8 b0 = *(const bf16x8*)(xlT_bf + (size_t)(cg + m) * 2048 + k);
            bf16x8 b1 = *(const bf16x8*)(xlT_bf + (size_t)(cg + 16 + m) * 2048 + k);
            accO0 = __builtin_amdgcn_mfma_f32_16x16x32_bf16(aa, b0, accO0, 0, 0, 0);
            accO1 = __builtin_amdgcn_mfma_f32_16x16x32_bf16(aa, b1, accO1, 0, 0, 0);
        }
    }

    // deg partial: reduce over m-lanes, combine 4 waves via LDS, plain store
    #pragma unroll
    for (int r = 0; r < 4; ++r) {
        float v = dega[r];
        v += __shfl_xor(v, 1);
        v += __shfl_xor(v, 2);
        v += __shfl_xor(v, 4);
        v += __shfl_xor(v, 8);
        if (m == 0) degS[w][q * 4 + r] = v;
    }
    __syncthreads();
    if (t < 16)
        degPart[bj * 2048 + i0 + t] =
            degS[0][t] + degS[1][t] + degS[2][t] + degS[3][t];

    // out partial: plain stores (block owns [bj][i0..i0+15][*])
    float* op = outPart + ((size_t)bj * 2048 + i0) * 128;
    #pragma unroll
    for (int r = 0; r < 4; ++r) {
        op[(q * 4 + r) * 128 + cg + m] = accO0[r];
        op[(q * 4 + r) * 128 + cg + 16 + m] = accO1[r];
    }
}

// ---------------- Kernel 3: out = relu(sum_p outPart / sum_p degPart) ----------------
__global__ __launch_bounds__(256) void k3_fin(
    const float* __restrict__ outPart, const float* __restrict__ degPart,
    float* __restrict__ out)
{
    int idx4 = (blockIdx.x * 256 + threadIdx.x) * 4;
    int row = idx4 >> 7;
    float4 s = make_float4(0.f, 0.f, 0.f, 0.f);
    float d = 0.f;
    #pragma unroll
    for (int p = 0; p < 8; ++p) {
        float4 v = *(const float4*)(&outPart[(size_t)p * 262144 + idx4]);
        s.x += v.x; s.y += v.y; s.z += v.z; s.w += v.w;
        d += degPart[p * 2048 + row];
    }
    float dinv = 1.0f / d;
    s.x = fmaxf(s.x * dinv, 0.f);
    s.y = fmaxf(s.y * dinv, 0.f);
    s.z = fmaxf(s.z * dinv, 0.f);
    s.w = fmaxf(s.w * dinv, 0.f);
    *(float4*)(&out[idx4]) = s;
}

extern "C" void kernel_launch(void* const* d_in, const int* in_sizes, int n_in,
                              void* d_out, int out_size, void* d_ws, size_t ws_size,
                              hipStream_t stream) {
    const float* x     = (const float*)d_in[0];
    const float* W0    = (const float*)d_in[2];
    const float* b0    = (const float*)d_in[3];
    const float* W1    = (const float*)d_in[4];
    const float* b1    = (const float*)d_in[5];
    const float* W2    = (const float*)d_in[6];
    const float* b2    = (const float*)d_in[7];
    const float* temp  = (const float*)d_in[8];
    const float* theta = (const float*)d_in[9];

    char* ws = (char*)d_ws;
    unsigned short* emb_bf = (unsigned short*)(ws);            // 262144 B
    unsigned short* xlT_bf = (unsigned short*)(ws + 262144);   // 524288 B
    float* sq      = (float*)(ws + 786432);                    //   8192 B
    float* degPart = (float*)(ws + 794624);                    //  65536 B
    float* outPart = (float*)(ws + 860160);                    // 8 MiB

    float* out  = (float*)d_out;              // [2048*128]
    float* adjw = (float*)d_out + 262144;     // [2048*2048]

    k1_mfma<<<128, 256, 0, stream>>>(x, W0, b0, W1, b1, W2, b2,
                                     emb_bf, xlT_bf, sq);
    k2f<<<dim3(128, 8), 256, 0, stream>>>(emb_bf, xlT_bf, sq, temp, theta,
                                          adjw, outPart, degPart);
    k3_fin<<<256, 256, 0, stream>>>(outPart, degPart, out);
}